// Round 1
// baseline (542.882 us; speedup 1.0000x reference)
//
#include <hip/hip_runtime.h>
#include <hip/hip_bf16.h>

typedef __attribute__((ext_vector_type(8))) short short8;
typedef __attribute__((ext_vector_type(4))) float f32x4;

#define NN    2048
#define DDIM  512
#define HDIM  512
#define PP    51
#define NBASE 30
#define PD    26112   // PP*DDIM

static __device__ __forceinline__ short f2bf(float f) {
  __hip_bfloat16 h = __float2bfloat16(f);
  short s;
  __builtin_memcpy(&s, &h, 2);
  return s;
}

#define GLOAD16(gsrc, ldst)                                                              \
  __builtin_amdgcn_global_load_lds((const __attribute__((address_space(1))) void*)(gsrc),\
                                   (__attribute__((address_space(3))) void*)(ldst),      \
                                   16, 0, 0)

// ---------------------------------------------------------------------------
// K0: vertex [2048,512] f32  ->  vT [512,2048] bf16   (transpose via LDS tile)
// ---------------------------------------------------------------------------
__global__ __launch_bounds__(256) void k_transpose(const float* __restrict__ vx,
                                                   short* __restrict__ vT) {
  __shared__ float tile[64][68];   // +4 pad breaks column-read conflicts
  const int t  = threadIdx.x;
  const int mt = blockIdx.x & 31, dt = blockIdx.x >> 5;
  const int m0 = mt * 64, d0 = dt * 64;

  const int r  = t >> 2;
  const int c0 = (t & 3) * 16;
  const float* src = vx + (size_t)(m0 + r) * DDIM + d0 + c0;
#pragma unroll
  for (int j = 0; j < 4; ++j) {
    f32x4 v = *(const f32x4*)(src + j * 4);
    tile[r][c0 + j * 4 + 0] = v[0];
    tile[r][c0 + j * 4 + 1] = v[1];
    tile[r][c0 + j * 4 + 2] = v[2];
    tile[r][c0 + j * 4 + 3] = v[3];
  }
  __syncthreads();
  const int c  = t >> 2;
  const int r0 = (t & 3) * 16;
  short8 o0, o1;
#pragma unroll
  for (int j = 0; j < 8; ++j) {
    o0[j] = f2bf(tile[r0 + j][c]);
    o1[j] = f2bf(tile[r0 + 8 + j][c]);
  }
  short* dst = vT + (size_t)(d0 + c) * NN + m0 + r0;
  *(short8*)(dst)     = o0;
  *(short8*)(dst + 8) = o1;
}

// ---------------------------------------------------------------------------
// K1: BmT [512][26112] bf16 ;  BmT[h][d'*51+p] = sum_b Wc[p,b]*W[(b*512+d')*512+h]
// one block per d' ; 512 threads = h
// ---------------------------------------------------------------------------
__global__ __launch_bounds__(512) void k_bmt(const float* __restrict__ W,
                                             const float* __restrict__ Wc,
                                             short* __restrict__ BmT) {
  __shared__ float wcs[PP * NBASE];   // 6120 B
  __shared__ short Lt[HDIM * PP];     // 52224 B  (Lt[h*51+p])
  const int t  = threadIdx.x;
  const int dp = blockIdx.x;

  for (int i = t; i < PP * NBASE; i += 512) wcs[i] = Wc[i];

  float wv[NBASE];
#pragma unroll
  for (int b = 0; b < NBASE; ++b)
    wv[b] = W[((size_t)(b * DDIM + dp)) * HDIM + t];
  __syncthreads();

#pragma unroll 1
  for (int p = 0; p < PP; ++p) {
    float acc = 0.f;
#pragma unroll
    for (int b = 0; b < NBASE; ++b) acc += wcs[p * NBASE + b] * wv[b];
    Lt[t * PP + p] = f2bf(acc);
  }
  __syncthreads();

  for (int idx = t; idx < HDIM * PP; idx += 512) {
    const int h = idx / PP;
    const int p = idx - h * PP;
    BmT[(size_t)h * PD + dp * PP + p] = Lt[idx];
  }
}

// ---------------------------------------------------------------------------
// K2: out[n,h] = B[h]
// ---------------------------------------------------------------------------
__global__ __launch_bounds__(512) void k_init(const float* __restrict__ B,
                                              float* __restrict__ out) {
  out[(size_t)blockIdx.x * HDIM + threadIdx.x] = B[threadIdx.x];
}

// ---------------------------------------------------------------------------
// G1: supports GEMM.  SF[n][p*512+d] = sum_m A[p,n,m]*vertex[m,d]  (bf16 out)
// grid = 51 * 16 * 2 ; tile 128(n) x 256(d) x BK64 ; 512 thr (8 waves 2x4)
// A: f32 reg-stage -> cvt -> swizzled LDS bf16 ; B: global_load_lds pre-swizzled
// ---------------------------------------------------------------------------
__global__ __launch_bounds__(512) void g_supports(const float* __restrict__ A,
                                                  const short* __restrict__ vT,
                                                  short* __restrict__ SF) {
  __shared__ __align__(16) char Asb[128 * 64 * 2];   // 16 KB
  __shared__ __align__(16) char Bsb[256 * 64 * 2];   // 32 KB
  const int t   = threadIdx.x;
  const int bid = blockIdx.x;
  const int p   = bid >> 5;
  const int rem = bid & 31;
  const int n0  = (rem >> 1) * 128;
  const int d0  = (rem & 1) * 256;
  const int lane = t & 63, w = t >> 6;
  const int wr = w >> 2, wc = w & 3;
  const int l15 = lane & 15, q4 = lane >> 4;

  const int arow = t >> 2;              // 0..127
  const int kb0  = (t & 3) << 5;        // byte col of first 16B chunk
  const int Xa   = (arow & 7) << 4;
  char* aw0 = Asb + arow * 128 + (kb0 ^ Xa);
  char* aw1 = Asb + arow * 128 + ((kb0 + 16) ^ Xa);

  const float* Abase = A + (size_t)p * NN * NN + (size_t)(n0 + arow) * NN + ((t & 3) << 4);

  f32x4 acc[4][4];
#pragma unroll
  for (int i = 0; i < 4; ++i)
#pragma unroll
    for (int j = 0; j < 4; ++j) acc[i][j] = (f32x4){0.f, 0.f, 0.f, 0.f};

  f32x4 ar0, ar1, ar2, ar3;
  {
    const f32x4* s = (const f32x4*)Abase;
    ar0 = s[0]; ar1 = s[1]; ar2 = s[2]; ar3 = s[3];
  }

  for (int kt = 0; kt < 32; ++kt) {
    __syncthreads();                       // previous compute done -> LDS free
    // --- stage A (cvt f32->bf16, swizzled ds_write) ---
    short8 s0, s1;
#pragma unroll
    for (int j = 0; j < 4; ++j) {
      s0[j]     = f2bf(ar0[j]);
      s0[j + 4] = f2bf(ar1[j]);
      s1[j]     = f2bf(ar2[j]);
      s1[j + 4] = f2bf(ar3[j]);
    }
    *(short8*)aw0 = s0;
    *(short8*)aw1 = s1;
    // --- stage B (async, pre-swizzled global source, linear LDS dest) ---
    const int m0k = kt << 6;
#pragma unroll
    for (int i = 0; i < 4; ++i) {
      const int L   = t * 16 + i * 8192;
      const int row = L >> 7;
      const int cb  = L & 127;
      const char* g = (const char*)vT + ((size_t)(d0 + row) * NN + m0k) * 2
                    + (cb ^ ((row & 7) << 4));
      GLOAD16(g, Bsb + L);
    }
    __syncthreads();                       // staged data visible
    // --- prefetch next A tile into regs (overlaps compute) ---
    if (kt + 1 < 32) {
      const f32x4* s = (const f32x4*)(Abase + (kt + 1) * 64);
      ar0 = s[0]; ar1 = s[1]; ar2 = s[2]; ar3 = s[3];
    }
    // --- compute: 2 k-steps x 16 MFMA ---
#pragma unroll
    for (int ks = 0; ks < 2; ++ks) {
      const int kb = ks * 64 + q4 * 16;
      short8 af[4], bfr[4];
#pragma unroll
      for (int mi = 0; mi < 4; ++mi) {
        const int row = wr * 64 + mi * 16 + l15;
        af[mi] = *(const short8*)(Asb + row * 128 + (kb ^ ((row & 7) << 4)));
      }
#pragma unroll
      for (int ni = 0; ni < 4; ++ni) {
        const int row = wc * 64 + ni * 16 + l15;
        bfr[ni] = *(const short8*)(Bsb + row * 128 + (kb ^ ((row & 7) << 4)));
      }
#pragma unroll
      for (int mi = 0; mi < 4; ++mi)
#pragma unroll
        for (int ni = 0; ni < 4; ++ni)
          acc[mi][ni] = __builtin_amdgcn_mfma_f32_16x16x32_bf16(af[mi], bfr[ni],
                                                                acc[mi][ni], 0, 0, 0);
    }
  }

  // epilogue: C row = 4*q4+qq (m89-verified), col = l15
#pragma unroll
  for (int mi = 0; mi < 4; ++mi) {
    const int nr = n0 + wr * 64 + mi * 16 + q4 * 4;
#pragma unroll
    for (int ni = 0; ni < 4; ++ni) {
      const int dc = d0 + wc * 64 + ni * 16 + l15;
#pragma unroll
      for (int qq = 0; qq < 4; ++qq)
        SF[(size_t)(nr + qq) * PD + p * DDIM + dc] = f2bf(acc[mi][ni][qq]);
    }
  }
}

// ---------------------------------------------------------------------------
// G2: out[n,h] += sum_r SF[n,r]*BmT[h,r]   (K split x17, f32 atomic epilogue)
// grid = 17 * 16 * 2 ; tile 128(n) x 256(h) x BK64, K-chunk 1536
// ---------------------------------------------------------------------------
__global__ __launch_bounds__(512) void g_out(const short* __restrict__ SF,
                                             const short* __restrict__ BmT,
                                             float* __restrict__ out) {
  __shared__ __align__(16) char Asb[128 * 64 * 2];
  __shared__ __align__(16) char Bsb[256 * 64 * 2];
  const int t   = threadIdx.x;
  const int bid = blockIdx.x;
  const int kc  = bid >> 5;          // 0..16
  const int rem = bid & 31;
  const int n0  = (rem >> 1) * 128;
  const int h0  = (rem & 1) * 256;
  const int rbase = kc * 1536;
  const int lane = t & 63, w = t >> 6;
  const int wr = w >> 2, wc = w & 3;
  const int l15 = lane & 15, q4 = lane >> 4;

  f32x4 acc[4][4];
#pragma unroll
  for (int i = 0; i < 4; ++i)
#pragma unroll
    for (int j = 0; j < 4; ++j) acc[i][j] = (f32x4){0.f, 0.f, 0.f, 0.f};

  for (int kt = 0; kt < 24; ++kt) {
    const int rk = rbase + (kt << 6);
    __syncthreads();
#pragma unroll
    for (int i = 0; i < 2; ++i) {
      const int L   = t * 16 + i * 8192;
      const int row = L >> 7, cb = L & 127;
      const char* g = (const char*)SF + ((size_t)(n0 + row) * PD + rk) * 2
                    + (cb ^ ((row & 7) << 4));
      GLOAD16(g, Asb + L);
    }
#pragma unroll
    for (int i = 0; i < 4; ++i) {
      const int L   = t * 16 + i * 8192;
      const int row = L >> 7, cb = L & 127;
      const char* g = (const char*)BmT + ((size_t)(h0 + row) * PD + rk) * 2
                    + (cb ^ ((row & 7) << 4));
      GLOAD16(g, Bsb + L);
    }
    __syncthreads();
#pragma unroll
    for (int ks = 0; ks < 2; ++ks) {
      const int kb = ks * 64 + q4 * 16;
      short8 af[4], bfr[4];
#pragma unroll
      for (int mi = 0; mi < 4; ++mi) {
        const int row = wr * 64 + mi * 16 + l15;
        af[mi] = *(const short8*)(Asb + row * 128 + (kb ^ ((row & 7) << 4)));
      }
#pragma unroll
      for (int ni = 0; ni < 4; ++ni) {
        const int row = wc * 64 + ni * 16 + l15;
        bfr[ni] = *(const short8*)(Bsb + row * 128 + (kb ^ ((row & 7) << 4)));
      }
#pragma unroll
      for (int mi = 0; mi < 4; ++mi)
#pragma unroll
        for (int ni = 0; ni < 4; ++ni)
          acc[mi][ni] = __builtin_amdgcn_mfma_f32_16x16x32_bf16(af[mi], bfr[ni],
                                                                acc[mi][ni], 0, 0, 0);
    }
  }

#pragma unroll
  for (int mi = 0; mi < 4; ++mi) {
    const int nr = n0 + wr * 64 + mi * 16 + q4 * 4;
#pragma unroll
    for (int ni = 0; ni < 4; ++ni) {
      const int hc = h0 + wc * 64 + ni * 16 + l15;
#pragma unroll
      for (int qq = 0; qq < 4; ++qq)
        atomicAdd(&out[(size_t)(nr + qq) * HDIM + hc], acc[mi][ni][qq]);
    }
  }
}

// ---------------------------------------------------------------------------
extern "C" void kernel_launch(void* const* d_in, const int* in_sizes, int n_in,
                              void* d_out, int out_size, void* d_ws, size_t ws_size,
                              hipStream_t stream) {
  const float* vertex = (const float*)d_in[0];
  const float* A      = (const float*)d_in[1];
  const float* W      = (const float*)d_in[2];
  const float* Wc     = (const float*)d_in[3];
  const float* B      = (const float*)d_in[4];
  float* out = (float*)d_out;

  char* ws  = (char*)d_ws;
  short* vT  = (short*)(ws);                          // 2 MB
  short* BmT = (short*)(ws + (size_t)(2  << 20));     // 26.75 MB
  short* SF  = (short*)(ws + (size_t)(32 << 20));     // 107 MB
  // total ws need: ~140.6 MB

  k_transpose<<<dim3(256),  dim3(256), 0, stream>>>(vertex, vT);
  k_bmt      <<<dim3(512),  dim3(512), 0, stream>>>(W, Wc, BmT);
  k_init     <<<dim3(2048), dim3(512), 0, stream>>>(B, out);
  g_supports <<<dim3(1632), dim3(512), 0, stream>>>(A, vT, SF);
  g_out      <<<dim3(544),  dim3(512), 0, stream>>>(SF, BmT, out);
}